// Round 18
// baseline (122.656 us; speedup 1.0000x reference)
//
#include <hip/hip_runtime.h>
#include <stdint.h>
#include <stddef.h>

// Problem constants (from reference): B=8, L=8192, D=1024, M=L/4=2048.
// Setup guarantees exactly M true mask positions per row -> counts == M.
#define B_ 8
#define L_ 8192
#define D_ 1024
#define M_ 2048
#define D4_ (D_/4)
#define TROWS_ 256           // rows per tile (one row per thread in list build)
#define NTILE_ (L_/TROWS_)   // 32 tiles per batch row
#define NBLK_ (B_*NTILE_)    // 256 blocks (1 per CU)

typedef float f4 __attribute__((ext_vector_type(4)));

// ---------------- workspace layout (bytes) ----------------
#define OFF_FLAG   ((size_t)0)                               // int u8flag
#define OFF_A      ((size_t)256)                             // float A[NBLK]
#define OFF_CNT    (OFF_A    + (size_t)NBLK_*4)              // int cnt[NBLK]
#define OFF_EZ     (OFF_CNT  + (size_t)NBLK_*4)              // float ez[NBLK][D]
#define WS_TOTAL   (OFF_EZ   + (size_t)NBLK_*D_*4)

// ---------------- kernel 1: per-tile list build + zero-init scan ------------
// One block per (b, tile k). Phase 1 (one ROW per thread): rebuild the tile's
// local chunk list from raw mask+prob via a block prefix sum. Phase 2 (one
// CHANNEL per thread): zero-init EMA scan over the tile's chunks -> segment
// end value ez, decay product A, count n. Mask dtype (u8 bool vs int32)
// detected per-block from the first 8 KiB; block 0 publishes it for fused.
__global__ __launch_bounds__(256)
void segend_kernel(const f4* __restrict__ x4,
                   const float* __restrict__ prob,
                   const void* __restrict__ mask_raw,
                   f4* __restrict__ ez4,
                   float* __restrict__ Aseg,
                   int* __restrict__ cnt,
                   int* __restrict__ u8out) {
    const int blk = blockIdx.x;          // b*NTILE_ + k
    const int b = blk >> 5;              // NTILE_ = 32
    const int k = blk & (NTILE_ - 1);
    const int t = threadIdx.x;
    const int l0 = k * TROWS_;

    __shared__ int   u8flag;
    __shared__ int   wsum[4];
    __shared__ int   pl[TROWS_ + 2];
    __shared__ float dl[TROWS_ + 2];

    if (t == 0) u8flag = 0;
    __syncthreads();
    {
        const uint32_t* mu = (const uint32_t*)mask_raw;
        uint32_t orv = 0;
        #pragma unroll
        for (int j = 0; j < 8; j++) orv |= mu[t * 8 + j];
        if (orv > 1u) atomicOr(&u8flag, 1);
    }
    pl[t] = L_; dl[t] = 1.0f;            // sentinel init
    if (t < 2) { pl[TROWS_ + t] = L_; dl[TROWS_ + t] = 1.0f; }
    __syncthreads();
    const bool u8 = (u8flag != 0);
    if (blk == 0 && t == 0) *u8out = u8 ? 1 : 0;

    // ---- phase 1: local chunk list (thread t owns row l0+t) ----
    const int gl = b * L_ + l0 + t;
    const int mv = u8 ? (((const uint8_t*)mask_raw)[gl] ? 1 : 0)
                      : (((const int*)mask_raw)[gl] ? 1 : 0);
    const float dv = fminf(fmaxf(1.0f - prob[gl], 0.0f), 1.0f);
    const int lane = t & 63, wid = t >> 6;
    int v = mv;
    #pragma unroll
    for (int off = 1; off < 64; off <<= 1) {
        int nn = __shfl_up(v, off, 64);
        if (lane >= off) v += nn;
    }
    if (lane == 63) wsum[wid] = v;
    __syncthreads();
    int acc = 0;
    #pragma unroll
    for (int w = 0; w < 4; w++) if (w < wid) acc += wsum[w];
    const int n = wsum[0] + wsum[1] + wsum[2] + wsum[3];
    const int excl = (v - mv) + acc;
    if (mv) { pl[excl] = l0 + t; dl[excl] = dv; }
    __syncthreads();

    // ---- phase 2: zero-init scan (thread t owns f4 channel t) ----
    f4 h = (f4)(0.0f);
    float A = 1.0f;
    const f4* xrow = x4 + (size_t)b * L_ * D4_;
    for (int g = 0; g < n; g += 8) {
        f4    xv[8];
        float dd[8];
        #pragma unroll
        for (int j = 0; j < 8; j++) {
            const int mm = g + j;
            const int mc = (mm < n) ? mm : 0;
            dd[j] = (mm < n) ? dl[mc] : 1.0f;
            xv[j] = xrow[(size_t)pl[mc] * D4_ + t];
        }
        #pragma unroll
        for (int j = 0; j < 8; j++) {
            h = dd[j] * h + (1.0f - dd[j]) * xv[j];
            A *= dd[j];
        }
    }
    ez4[(size_t)blk * D4_ + t] = h;
    if (t == 0) { Aseg[blk] = A; cnt[blk] = n; }
}

// ---------------- kernel 2: fused carry + scan + scatter (8-deep stream) ----
// One block per (b, tile k). Rebuilds the tile's local chunk list (same
// prefix sum as segend), then RECONSTRUCTS its carry-in in-block: c = state,
// then c = ez[j] + A[j]*c for j < k (ez reads are L2/L3-hot, A/cnt via LDS).
// live = (sum cnt[0..k-1] > 0). Block k = NTILE_-1 also applies its own
// (ez, A) and writes new_state. Then the fixed 256-row NT stream with 8-row
// lookahead; ADV advances h at chunk boundaries with double-prefetched x.
__global__ __launch_bounds__(256)
void fused_kernel(const f4* __restrict__ x4,
                  const f4* __restrict__ res4,
                  const float* __restrict__ prob,
                  const void* __restrict__ mask_raw,
                  const int* __restrict__ u8in,
                  const f4* __restrict__ ez4,
                  const float* __restrict__ Aseg,
                  const int* __restrict__ cnt,
                  const float* __restrict__ state,
                  f4* __restrict__ out4,
                  float* __restrict__ newstate) {
    const int blk = blockIdx.x;          // b*NTILE_ + k
    const int b = blk >> 5;              // NTILE_ = 32
    const int k = blk & (NTILE_ - 1);
    const int t = threadIdx.x;
    const int l0 = k * TROWS_;

    __shared__ int   wsum[4];
    __shared__ int   pl[TROWS_ + 2];
    __shared__ float dl[TROWS_ + 2];
    __shared__ float Al[NTILE_];
    __shared__ int   Cl[NTILE_];

    pl[t] = L_; dl[t] = 1.0f;            // sentinel init
    if (t < 2) { pl[TROWS_ + t] = L_; dl[TROWS_ + t] = 1.0f; }
    if (t < NTILE_) {
        Al[t] = Aseg[b * NTILE_ + t];
        Cl[t] = cnt[b * NTILE_ + t];
    }
    const bool u8 = (*u8in != 0);        // uniform scalar load

    const int gl = b * L_ + l0 + t;
    const int mv = u8 ? (((const uint8_t*)mask_raw)[gl] ? 1 : 0)
                      : (((const int*)mask_raw)[gl] ? 1 : 0);
    const float dv = fminf(fmaxf(1.0f - prob[gl], 0.0f), 1.0f);
    const int lane = t & 63, wid = t >> 6;
    int v = mv;
    #pragma unroll
    for (int off = 1; off < 64; off <<= 1) {
        int nn = __shfl_up(v, off, 64);
        if (lane >= off) v += nn;
    }
    if (lane == 63) wsum[wid] = v;
    __syncthreads();                     // covers sentinels, Al/Cl, wsum
    int acc = 0;
    #pragma unroll
    for (int w = 0; w < 4; w++) if (w < wid) acc += wsum[w];
    const int excl = (v - mv) + acc;
    if (mv) { pl[excl] = l0 + t; dl[excl] = dv; }

    // ---- carry reconstruction: c = state, then chain over tiles 0..k-1 ----
    const f4* ezrow = ez4 + (size_t)b * NTILE_ * D4_;
    f4 c = ((const f4*)state)[(size_t)b * D4_ + t];
    int cc = 0;
    for (int j0 = 0; j0 < k; j0 += 8) {
        f4 e[8];
        #pragma unroll
        for (int j = 0; j < 8; j++) {
            const int jj = j0 + j;
            const int jc = (jj < k) ? jj : 0;
            e[j] = ezrow[(size_t)jc * D4_ + t];
        }
        #pragma unroll
        for (int j = 0; j < 8; j++) {
            const int jj = j0 + j;
            if (jj < k) {
                c = e[j] + Al[jj] * c;
                cc += Cl[jj];
            }
        }
    }
    if (k == NTILE_ - 1) {               // finalize new_state (last tile)
        const f4 cfin = ezrow[(size_t)k * D4_ + t] + Al[k] * c;
        ((f4*)newstate)[(size_t)b * D4_ + t] = cfin;
    }
    f4 h = c;                            // state entering this tile
    float live = (cc > 0) ? 1.0f : 0.0f;
    __syncthreads();                     // pl/dl scatter complete

    const f4* xrow = x4 + (size_t)b * L_ * D4_;
    const f4* resrow = res4 + (size_t)b * L_ * D4_;
    f4*       outrow = out4 + (size_t)b * L_ * D4_;

    int mi = 0;
    int nextb = pl[0];
    int a0 = (pl[0] < L_) ? pl[0] : 0;
    int a1 = (pl[1] < L_) ? pl[1] : 0;
    f4 xn  = xrow[(size_t)a0 * D4_ + t];
    f4 xn2 = xrow[(size_t)a1 * D4_ + t];
    int l = l0;

    #define ADV(K, HH, LV)                                                \
        if (l + (K) == nextb) {                                           \
            const float d_ = dl[mi];                                      \
            h = d_ * h + (1.0f - d_) * xn;                                \
            live = 1.0f;                                                  \
            xn = xn2;                                                     \
            ++mi;                                                         \
            nextb = pl[mi];                                               \
            const int nr_ = (pl[mi + 1] < L_) ? pl[mi + 1] : 0;           \
            xn2 = xrow[(size_t)nr_ * D4_ + t];                            \
        }                                                                 \
        HH = h; LV = live;

    #define STORE4                                                        \
        {                                                                 \
            f4 h0, h1, h2, h3;                                            \
            float v0, v1, v2, v3;                                         \
            ADV(0, h0, v0); ADV(1, h1, v1); ADV(2, h2, v2); ADV(3, h3, v3);\
            __builtin_nontemporal_store(c0 + v0 * h0, outrow + (size_t)(l + 0) * D4_ + t); \
            __builtin_nontemporal_store(c1 + v1 * h1, outrow + (size_t)(l + 1) * D4_ + t); \
            __builtin_nontemporal_store(c2 + v2 * h2, outrow + (size_t)(l + 2) * D4_ + t); \
            __builtin_nontemporal_store(c3 + v3 * h3, outrow + (size_t)(l + 3) * D4_ + t); \
        }

    // prime: 8 rows of residual in flight
    f4 c0 = __builtin_nontemporal_load(resrow + (size_t)(l + 0) * D4_ + t);
    f4 c1 = __builtin_nontemporal_load(resrow + (size_t)(l + 1) * D4_ + t);
    f4 c2 = __builtin_nontemporal_load(resrow + (size_t)(l + 2) * D4_ + t);
    f4 c3 = __builtin_nontemporal_load(resrow + (size_t)(l + 3) * D4_ + t);
    f4 c4 = __builtin_nontemporal_load(resrow + (size_t)(l + 4) * D4_ + t);
    f4 c5 = __builtin_nontemporal_load(resrow + (size_t)(l + 5) * D4_ + t);
    f4 c6 = __builtin_nontemporal_load(resrow + (size_t)(l + 6) * D4_ + t);
    f4 c7 = __builtin_nontemporal_load(resrow + (size_t)(l + 7) * D4_ + t);

    // main: (TROWS_/4 - 2) groups with 8-row lookahead
    for (int g = 0; g < (TROWS_ / 4) - 2; ++g) {
        f4 n0 = __builtin_nontemporal_load(resrow + (size_t)(l +  8) * D4_ + t);
        f4 n1 = __builtin_nontemporal_load(resrow + (size_t)(l +  9) * D4_ + t);
        f4 n2 = __builtin_nontemporal_load(resrow + (size_t)(l + 10) * D4_ + t);
        f4 n3 = __builtin_nontemporal_load(resrow + (size_t)(l + 11) * D4_ + t);
        STORE4;
        c0 = c4; c1 = c5; c2 = c6; c3 = c7;
        c4 = n0; c5 = n1; c6 = n2; c7 = n3;
        l += 4;
    }
    // epilogue: last two groups
    STORE4;
    c0 = c4; c1 = c5; c2 = c6; c3 = c7;
    l += 4;
    STORE4;
    #undef STORE4
    #undef ADV
}

extern "C" void kernel_launch(void* const* d_in, const int* in_sizes, int n_in,
                              void* d_out, int out_size, void* d_ws, size_t ws_size,
                              hipStream_t stream) {
    const float* x        = (const float*)d_in[0];
    const float* residual = (const float*)d_in[1];
    const float* prob     = (const float*)d_in[2];
    const void*  mask     = d_in[3];
    const float* state    = (const float*)d_in[4];

    float* out       = (float*)d_out;                       // (B,L,D)
    float* new_state = out + (size_t)B_ * L_ * D_;          // (B,D)

    if (ws_size < WS_TOTAL) return;  // fail loudly (zeros) rather than corrupt

    char* ws = (char*)d_ws;
    int*   u8flag = (int*)  (ws + OFF_FLAG);
    float* Aseg   = (float*)(ws + OFF_A);
    int*   cnt    = (int*)  (ws + OFF_CNT);
    float* ez     = (float*)(ws + OFF_EZ);

    segend_kernel<<<NBLK_, 256, 0, stream>>>(
        (const f4*)x, prob, mask, (f4*)ez, Aseg, cnt, u8flag);

    fused_kernel<<<NBLK_, 256, 0, stream>>>(
        (const f4*)x, (const f4*)residual, prob, mask, u8flag,
        (const f4*)ez, Aseg, cnt, state, (f4*)out, new_state);
}

// Round 19
// 119.412 us; speedup vs baseline: 1.0272x; 1.0272x over previous
//
#include <hip/hip_runtime.h>
#include <stdint.h>
#include <stddef.h>

// Problem constants (from reference): B=8, L=8192, D=1024, M=L/4=2048.
// Setup guarantees exactly M true mask positions per row -> counts == M.
#define B_ 8
#define L_ 8192
#define D_ 1024
#define M_ 2048
#define D4_ (D_/4)
#define TROWS_ 256           // rows per tile (one row per thread in list build)
#define NTILE_ (L_/TROWS_)   // 32 tiles per batch row
#define NBLK_ (B_*NTILE_)    // 256 blocks (1 per CU)

typedef float f4 __attribute__((ext_vector_type(4)));

// ---------------- workspace layout (bytes) ----------------
#define OFF_FLAG   ((size_t)0)                               // int u8flag
#define OFF_A      ((size_t)256)                             // float A[NBLK]
#define OFF_CNT    (OFF_A    + (size_t)NBLK_*4)              // int cnt[NBLK]
#define OFF_LIVE   (OFF_CNT  + (size_t)NBLK_*4)              // int live[NBLK]
#define OFF_EZ     (OFF_LIVE + (size_t)NBLK_*4)              // float ez[NBLK][D]
#define OFF_HINIT  (OFF_EZ   + (size_t)NBLK_*D_*4)           // float hinit[NBLK][D]
#define WS_TOTAL   (OFF_HINIT + (size_t)NBLK_*D_*4)

// ---------------- kernel 1: per-tile list build + zero-init scan ------------
// One block per (b, tile k). Phase 1 (one ROW per thread): rebuild the tile's
// local chunk list from raw mask+prob via a block prefix sum. Phase 2 (one
// CHANNEL per thread): zero-init EMA scan over the tile's chunks -> segment
// end value ez, decay product A, count n. Mask dtype (u8 bool vs int32)
// detected per-block from the first 8 KiB; block 0 publishes it for fused.
__global__ __launch_bounds__(256)
void segend_kernel(const f4* __restrict__ x4,
                   const float* __restrict__ prob,
                   const void* __restrict__ mask_raw,
                   f4* __restrict__ ez4,
                   float* __restrict__ Aseg,
                   int* __restrict__ cnt,
                   int* __restrict__ u8out) {
    const int blk = blockIdx.x;          // b*NTILE_ + k
    const int b = blk >> 5;              // NTILE_ = 32
    const int k = blk & (NTILE_ - 1);
    const int t = threadIdx.x;
    const int l0 = k * TROWS_;

    __shared__ int   u8flag;
    __shared__ int   wsum[4];
    __shared__ int   pl[TROWS_ + 2];
    __shared__ float dl[TROWS_ + 2];

    if (t == 0) u8flag = 0;
    __syncthreads();
    {
        const uint32_t* mu = (const uint32_t*)mask_raw;
        uint32_t orv = 0;
        #pragma unroll
        for (int j = 0; j < 8; j++) orv |= mu[t * 8 + j];
        if (orv > 1u) atomicOr(&u8flag, 1);
    }
    pl[t] = L_; dl[t] = 1.0f;            // sentinel init
    if (t < 2) { pl[TROWS_ + t] = L_; dl[TROWS_ + t] = 1.0f; }
    __syncthreads();
    const bool u8 = (u8flag != 0);
    if (blk == 0 && t == 0) *u8out = u8 ? 1 : 0;

    // ---- phase 1: local chunk list (thread t owns row l0+t) ----
    const int gl = b * L_ + l0 + t;
    const int mv = u8 ? (((const uint8_t*)mask_raw)[gl] ? 1 : 0)
                      : (((const int*)mask_raw)[gl] ? 1 : 0);
    const float dv = fminf(fmaxf(1.0f - prob[gl], 0.0f), 1.0f);
    const int lane = t & 63, wid = t >> 6;
    int v = mv;
    #pragma unroll
    for (int off = 1; off < 64; off <<= 1) {
        int nn = __shfl_up(v, off, 64);
        if (lane >= off) v += nn;
    }
    if (lane == 63) wsum[wid] = v;
    __syncthreads();
    int acc = 0;
    #pragma unroll
    for (int w = 0; w < 4; w++) if (w < wid) acc += wsum[w];
    const int n = wsum[0] + wsum[1] + wsum[2] + wsum[3];
    const int excl = (v - mv) + acc;
    if (mv) { pl[excl] = l0 + t; dl[excl] = dv; }
    __syncthreads();

    // ---- phase 2: zero-init scan (thread t owns f4 channel t) ----
    f4 h = (f4)(0.0f);
    float A = 1.0f;
    const f4* xrow = x4 + (size_t)b * L_ * D4_;
    for (int g = 0; g < n; g += 8) {
        f4    xv[8];
        float dd[8];
        #pragma unroll
        for (int j = 0; j < 8; j++) {
            const int mm = g + j;
            const int mc = (mm < n) ? mm : 0;
            dd[j] = (mm < n) ? dl[mc] : 1.0f;
            xv[j] = xrow[(size_t)pl[mc] * D4_ + t];
        }
        #pragma unroll
        for (int j = 0; j < 8; j++) {
            h = dd[j] * h + (1.0f - dd[j]) * xv[j];
            A *= dd[j];
        }
    }
    ez4[(size_t)blk * D4_ + t] = h;
    if (t == 0) { Aseg[blk] = A; cnt[blk] = n; }
}

// ---------------- kernel 2: carry propagation across tiles + new_state ------
// grid (B, 16), block 64: scalar channel per thread (8192 parallel chains).
// hinit[b][k] = ema state ENTERING tile k (c_0 = state); live[b][k] = any
// chunk before tile k. ez prefetched in batches of 8.
__global__ __launch_bounds__(64)
void combine_kernel(const float* __restrict__ ez,
                    const float* __restrict__ Aseg,
                    const int* __restrict__ cnt,
                    const float* __restrict__ state,
                    float* __restrict__ hinit,
                    int* __restrict__ live,
                    float* __restrict__ newstate) {
    const int b = blockIdx.x;
    const int ch = blockIdx.y * 64 + threadIdx.x;   // scalar channel 0..1023
    __shared__ float Al[NTILE_];
    __shared__ int   Cl[NTILE_];
    if (threadIdx.x < NTILE_) {
        Al[threadIdx.x] = Aseg[b * NTILE_ + threadIdx.x];
        Cl[threadIdx.x] = cnt[b * NTILE_ + threadIdx.x];
    }
    __syncthreads();

    float c = state[(size_t)b * D_ + ch];
    for (int s0 = 0; s0 < NTILE_; s0 += 8) {
        float e[8];
        #pragma unroll
        for (int j = 0; j < 8; j++)
            e[j] = ez[((size_t)b * NTILE_ + s0 + j) * D_ + ch];
        #pragma unroll
        for (int j = 0; j < 8; j++) {
            hinit[((size_t)b * NTILE_ + s0 + j) * D_ + ch] = c;
            c = fmaf(Al[s0 + j], c, e[j]);
        }
    }
    newstate[(size_t)b * D_ + ch] = c;   // counts == M guaranteed
    if (blockIdx.y == 0 && threadIdx.x == 0) {
        int cc = 0;
        for (int kk = 0; kk < NTILE_; kk++) {
            live[b * NTILE_ + kk] = (cc > 0) ? 1 : 0;
            cc += Cl[kk];
        }
    }
}

// ---------------- kernel 3: PURE-STREAM fused scan + scatter (8-deep) -------
// One block per (b, tile). Prime loads (8 residual rows + hinit seed) issued
// FIRST so HBM fetch overlaps the LDS list build. Then rebuild the tile's
// local chunk list (same prefix sum as segend) and run the fixed 256-row NT
// stream with 8-row lookahead; ADV advances h at chunk boundaries with
// double-prefetched x gathers (L3-hot from segend).
__global__ __launch_bounds__(256)
void fused_kernel(const f4* __restrict__ x4,
                  const f4* __restrict__ res4,
                  const float* __restrict__ prob,
                  const void* __restrict__ mask_raw,
                  const int* __restrict__ u8in,
                  const int* __restrict__ liveA,
                  const f4* __restrict__ hinit4,
                  f4* __restrict__ out4) {
    const int blk = blockIdx.x;          // b*NTILE_ + k
    const int b = blk >> 5;              // NTILE_ = 32
    const int k = blk & (NTILE_ - 1);
    const int t = threadIdx.x;
    const int l0 = k * TROWS_;

    const f4* resrow = res4 + (size_t)b * L_ * D4_;
    f4*       outrow = out4 + (size_t)b * L_ * D4_;

    // ---- issue prime loads FIRST: 8 residual rows + hinit seed in flight ----
    int l = l0;
    f4 c0 = __builtin_nontemporal_load(resrow + (size_t)(l + 0) * D4_ + t);
    f4 c1 = __builtin_nontemporal_load(resrow + (size_t)(l + 1) * D4_ + t);
    f4 c2 = __builtin_nontemporal_load(resrow + (size_t)(l + 2) * D4_ + t);
    f4 c3 = __builtin_nontemporal_load(resrow + (size_t)(l + 3) * D4_ + t);
    f4 c4 = __builtin_nontemporal_load(resrow + (size_t)(l + 4) * D4_ + t);
    f4 c5 = __builtin_nontemporal_load(resrow + (size_t)(l + 5) * D4_ + t);
    f4 c6 = __builtin_nontemporal_load(resrow + (size_t)(l + 6) * D4_ + t);
    f4 c7 = __builtin_nontemporal_load(resrow + (size_t)(l + 7) * D4_ + t);
    f4 h = hinit4[(size_t)blk * D4_ + t];   // state entering this tile
    float live = liveA[blk] ? 1.0f : 0.0f;

    __shared__ int   wsum[4];
    __shared__ int   pl[TROWS_ + 2];
    __shared__ float dl[TROWS_ + 2];

    pl[t] = L_; dl[t] = 1.0f;            // sentinel init
    if (t < 2) { pl[TROWS_ + t] = L_; dl[TROWS_ + t] = 1.0f; }
    const bool u8 = (*u8in != 0);        // uniform scalar load

    const int gl = b * L_ + l0 + t;
    const int mv = u8 ? (((const uint8_t*)mask_raw)[gl] ? 1 : 0)
                      : (((const int*)mask_raw)[gl] ? 1 : 0);
    const float dv = fminf(fmaxf(1.0f - prob[gl], 0.0f), 1.0f);
    const int lane = t & 63, wid = t >> 6;
    int v = mv;
    #pragma unroll
    for (int off = 1; off < 64; off <<= 1) {
        int nn = __shfl_up(v, off, 64);
        if (lane >= off) v += nn;
    }
    if (lane == 63) wsum[wid] = v;
    __syncthreads();                     // covers sentinel init + wsum
    int acc = 0;
    #pragma unroll
    for (int w = 0; w < 4; w++) if (w < wid) acc += wsum[w];
    const int excl = (v - mv) + acc;
    if (mv) { pl[excl] = l0 + t; dl[excl] = dv; }
    __syncthreads();

    const f4* xrow = x4 + (size_t)b * L_ * D4_;

    int mi = 0;
    int nextb = pl[0];
    int a0 = (pl[0] < L_) ? pl[0] : 0;
    int a1 = (pl[1] < L_) ? pl[1] : 0;
    f4 xn  = xrow[(size_t)a0 * D4_ + t];
    f4 xn2 = xrow[(size_t)a1 * D4_ + t];

    #define ADV(K, HH, LV)                                                \
        if (l + (K) == nextb) {                                           \
            const float d_ = dl[mi];                                      \
            h = d_ * h + (1.0f - d_) * xn;                                \
            live = 1.0f;                                                  \
            xn = xn2;                                                     \
            ++mi;                                                         \
            nextb = pl[mi];                                               \
            const int nr_ = (pl[mi + 1] < L_) ? pl[mi + 1] : 0;           \
            xn2 = xrow[(size_t)nr_ * D4_ + t];                            \
        }                                                                 \
        HH = h; LV = live;

    #define STORE4                                                        \
        {                                                                 \
            f4 h0, h1, h2, h3;                                            \
            float v0, v1, v2, v3;                                         \
            ADV(0, h0, v0); ADV(1, h1, v1); ADV(2, h2, v2); ADV(3, h3, v3);\
            __builtin_nontemporal_store(c0 + v0 * h0, outrow + (size_t)(l + 0) * D4_ + t); \
            __builtin_nontemporal_store(c1 + v1 * h1, outrow + (size_t)(l + 1) * D4_ + t); \
            __builtin_nontemporal_store(c2 + v2 * h2, outrow + (size_t)(l + 2) * D4_ + t); \
            __builtin_nontemporal_store(c3 + v3 * h3, outrow + (size_t)(l + 3) * D4_ + t); \
        }

    // main: (TROWS_/4 - 2) groups with 8-row lookahead
    for (int g = 0; g < (TROWS_ / 4) - 2; ++g) {
        f4 n0 = __builtin_nontemporal_load(resrow + (size_t)(l +  8) * D4_ + t);
        f4 n1 = __builtin_nontemporal_load(resrow + (size_t)(l +  9) * D4_ + t);
        f4 n2 = __builtin_nontemporal_load(resrow + (size_t)(l + 10) * D4_ + t);
        f4 n3 = __builtin_nontemporal_load(resrow + (size_t)(l + 11) * D4_ + t);
        STORE4;
        c0 = c4; c1 = c5; c2 = c6; c3 = c7;
        c4 = n0; c5 = n1; c6 = n2; c7 = n3;
        l += 4;
    }
    // epilogue: last two groups
    STORE4;
    c0 = c4; c1 = c5; c2 = c6; c3 = c7;
    l += 4;
    STORE4;
    #undef STORE4
    #undef ADV
}

extern "C" void kernel_launch(void* const* d_in, const int* in_sizes, int n_in,
                              void* d_out, int out_size, void* d_ws, size_t ws_size,
                              hipStream_t stream) {
    const float* x        = (const float*)d_in[0];
    const float* residual = (const float*)d_in[1];
    const float* prob     = (const float*)d_in[2];
    const void*  mask     = d_in[3];
    const float* state    = (const float*)d_in[4];

    float* out       = (float*)d_out;                       // (B,L,D)
    float* new_state = out + (size_t)B_ * L_ * D_;          // (B,D)

    if (ws_size < WS_TOTAL) return;  // fail loudly (zeros) rather than corrupt

    char* ws = (char*)d_ws;
    int*   u8flag = (int*)  (ws + OFF_FLAG);
    float* Aseg   = (float*)(ws + OFF_A);
    int*   cnt    = (int*)  (ws + OFF_CNT);
    int*   live   = (int*)  (ws + OFF_LIVE);
    float* ez     = (float*)(ws + OFF_EZ);
    float* hinit  = (float*)(ws + OFF_HINIT);

    segend_kernel<<<NBLK_, 256, 0, stream>>>(
        (const f4*)x, prob, mask, (f4*)ez, Aseg, cnt, u8flag);

    combine_kernel<<<dim3(B_, 16), 64, 0, stream>>>(
        ez, Aseg, cnt, state, hinit, live, new_state);

    fused_kernel<<<NBLK_, 256, 0, stream>>>(
        (const f4*)x, (const f4*)residual, prob, mask, u8flag, live,
        (const f4*)hinit, (f4*)out);
}